// Round 3
// baseline (4755.999 us; speedup 1.0000x reference)
//
#include <hip/hip_runtime.h>

#define T_LEN 256
#define B_SZ  64
#define H_SZ  1024
#define G4H   4096
#define HB    (B_SZ * H_SZ)              // 65536
#define NBLK  256                        // compute WGs ONLY — no extra blocks

typedef __attribute__((ext_vector_type(8))) short short8;
typedef __attribute__((ext_vector_type(4))) float float4_;
typedef __attribute__((ext_vector_type(4))) unsigned int uint4_;
typedef __attribute__((ext_vector_type(8))) unsigned int uint8_;

__device__ __forceinline__ unsigned short bf16_rne(float x) {
  unsigned u = __builtin_bit_cast(unsigned, x);
  unsigned r = u + 0x7FFFu + ((u >> 16) & 1u);
  return (unsigned short)(r >> 16);
}
__device__ __forceinline__ float bf16_to_f32(unsigned short s) {
  unsigned u = ((unsigned)s) << 16;
  return __builtin_bit_cast(float, u);
}

// ---------- prep: x fp32 -> packed split-bf16 (hi | lo<<16) dwords ----------
__global__ __launch_bounds__(256)
void pack_x(const float* __restrict__ src, unsigned* __restrict__ dst) {
  const size_t i = ((size_t)blockIdx.x * 256 + threadIdx.x) * 4;
  float4_ v = *(const float4_*)(src + i);
  uint4_ o;
  #pragma unroll
  for (int j = 0; j < 4; ++j) {
    const unsigned short h = bf16_rne(v[j]);
    const unsigned short l = bf16_rne(v[j] - bf16_to_f32(h));
    o[j] = (unsigned)h | ((unsigned)l << 16);
  }
  *(uint4_*)(dst + i) = o;
}

// ---------- prep: h0 -> ring slot 7 (t = -1) + zero sync state ----------
__global__ __launch_bounds__(256)
void init_h(const float* __restrict__ h0, unsigned* __restrict__ ringp,
            unsigned* __restrict__ bar) {
  if (blockIdx.x == 0) {
    #pragma unroll
    for (int j = 0; j < 4; ++j) bar[threadIdx.x * 4 + j] = 0u;
  }
  const int e0 = (blockIdx.x * 256 + threadIdx.x) * 4;
  #pragma unroll
  for (int j = 0; j < 4; ++j) {
    const int e = e0 + j;                 // [2][B][H] = 131072 elems
    const int l = e >> 16;
    const int rem = e & (HB - 1);
    const float v = h0[e];
    const unsigned hh = bf16_rne(v);
    const unsigned ll = bf16_rne(v - bf16_to_f32((unsigned short)hh));
    ringp[(size_t)(l * 8 + 7) * HB + rem] = hh | (ll << 16);
  }
}

__device__ __forceinline__ void poll_ge(const unsigned* p, unsigned v) {
  while (__hip_atomic_load(p, __ATOMIC_RELAXED, __HIP_MEMORY_SCOPE_AGENT) < v)
    __builtin_amdgcn_s_sleep(1);
}

// leader wave: poll all 128 own-layer slots (64 lanes x 2), publish go x4
__device__ __forceinline__ void leader_wait_publish(const unsigned* slots,
                                                    unsigned* gow,
                                                    unsigned v, int lane) {
  for (;;) {
    const unsigned a = __hip_atomic_load(slots + lane, __ATOMIC_RELAXED,
                                         __HIP_MEMORY_SCOPE_AGENT);
    const unsigned b = __hip_atomic_load(slots + lane + 64, __ATOMIC_RELAXED,
                                         __HIP_MEMORY_SCOPE_AGENT);
    if (__all((int)(a >= v && b >= v))) break;
    __builtin_amdgcn_s_sleep(1);
  }
  if (lane < 4)
    __hip_atomic_store(gow + lane * 32, v, __ATOMIC_RELAXED,
                       __HIP_MEMORY_SCOPE_AGENT);
}

// one input-side (or recurrent-side) half-GEMM: 96 MFMAs per wave.
__device__ __forceinline__ void accum_side(float4_ (&acc)[4][2],
                                           const unsigned* src,
                                           const short8 (&wp)[2][2][4],
                                           const int nn, const int quad,
                                           const int wave) {
  #pragma unroll
  for (int kb = 0; kb < 4; ++kb) {
    const int k0 = wave * 128 + kb * 32 + quad * 8;
    #pragma unroll
    for (int m = 0; m < 4; ++m) {
      const int row = m * 16 + nn;
      const uint8_ u = *(const uint8_*)(src + (size_t)row * H_SZ + k0);
      uint4_ h4, l4;
      #pragma unroll
      for (int r = 0; r < 4; ++r) {
        h4[r] = __builtin_amdgcn_perm(u[2 * r + 1], u[2 * r], 0x05040100u);
        l4[r] = __builtin_amdgcn_perm(u[2 * r + 1], u[2 * r], 0x07060302u);
      }
      const short8 hi = __builtin_bit_cast(short8, h4);
      const short8 lo = __builtin_bit_cast(short8, l4);
      #pragma unroll
      for (int nt = 0; nt < 2; ++nt) {
        acc[m][nt] = __builtin_amdgcn_mfma_f32_16x16x32_bf16(hi, wp[0][nt][kb], acc[m][nt], 0, 0, 0);
        acc[m][nt] = __builtin_amdgcn_mfma_f32_16x16x32_bf16(lo, wp[0][nt][kb], acc[m][nt], 0, 0, 0);
        acc[m][nt] = __builtin_amdgcn_mfma_f32_16x16x32_bf16(hi, wp[1][nt][kb], acc[m][nt], 0, 0, 0);
      }
    }
  }
}

// ---------- persistent LSTM: per-layer decoupled pipelines, leader barrier ----
// Layer l runs its own t=0..255, synced among its 128 WGs via RMW-free slot
// stores + leader WG (cb==0) publishing go. Cross-layer gates:
//   layer1 prologue/shadow (reads h0(t)) : go0 >= t+1 / t+2
//   layer0 ring-slot reuse               : go1 >= t-7   (8-deep ring)
// bar layout (dwords): slots0[0..127] slots1[128..255]
//   go0 @256+{0,32,64,96}, go1 @384+{0,32,64,96}
__global__ __launch_bounds__(512, 2)
void lstm_persist(const unsigned* __restrict__ xp,     // packed x [T][B][H]
                  const float* __restrict__ c0_in,
                  const float* __restrict__ Wih,       // fp32 [L][4H][H]
                  const float* __restrict__ Whh,
                  const float* __restrict__ bih,
                  const float* __restrict__ bhh,
                  unsigned* __restrict__ ringp,        // [L][8 slots][B][H] packed
                  float* __restrict__ out,
                  unsigned* __restrict__ bar)
{
  const int wg   = blockIdx.x;
  const int tid  = threadIdx.x;
  const int lane = tid & 63;
  const int wave = tid >> 6;

  const int layer = wg >> 7;
  const int cb    = wg & 127;
  const int nn    = lane & 15;
  const int quad  = lane >> 4;

  __shared__ float lds[8][64][36];

  int growA[2];
  #pragma unroll
  for (int nt = 0; nt < 2; ++nt) {
    const int q = nt * 2 + (nn >> 3);
    growA[nt] = q * H_SZ + cb * 8 + (nn & 7);
  }

  // ---- one-time: fp32 weights -> split-bf16 register fragments
  short8 wreg[2][2][2][4];  // [mat(ih,hh)][plane(hi,lo)][ntile][kb]
  #pragma unroll
  for (int mat = 0; mat < 2; ++mat) {
    const float* wsrc = mat ? Whh : Wih;
    #pragma unroll
    for (int nt = 0; nt < 2; ++nt)
      #pragma unroll
      for (int kb = 0; kb < 4; ++kb) {
        const float* p = wsrc + ((size_t)layer * G4H + growA[nt]) * H_SZ +
                         wave * 128 + kb * 32 + quad * 8;
        short8 hi, lo;
        #pragma unroll
        for (int j = 0; j < 8; ++j) {
          const float v = p[j];
          const unsigned short h = bf16_rne(v);
          hi[j] = (short)h;
          lo[j] = (short)bf16_rne(v - bf16_to_f32(h));
        }
        wreg[mat][0][nt][kb] = hi;
        wreg[mat][1][nt][kb] = lo;
      }
  }

  // ---- reduce-phase mapping + bias preload
  const int rb    = tid >> 3;
  const int rhc   = tid & 7;
  const int rhcol = cb * 8 + rhc;
  float4_ bias4;
  #pragma unroll
  for (int q = 0; q < 4; ++q)
    bias4[q] = bih[layer * G4H + q * H_SZ + rhcol] +
               bhh[layer * G4H + q * H_SZ + rhcol];

  unsigned*       slotp     = bar + layer * 128 + cb;
  const unsigned* slots_own = bar + layer * 128;
  unsigned*       go_own_w  = bar + 256 + layer * 128;
  const unsigned* go_own    = bar + 256 + layer * 128 + ((cb >> 5) & 3) * 32;
  const unsigned* go_oth    = bar + 256 + (1 - layer) * 128 + ((cb >> 5) & 3) * 32;

  const unsigned* ring_own = ringp + (size_t)layer * 8 * HB;
  const unsigned* ring_l0  = ringp;

  float creg = 0.f;
  float4_ acc[4][2];
  #pragma unroll
  for (int m = 0; m < 4; ++m)
    #pragma unroll
    for (int nt = 0; nt < 2; ++nt)
      acc[m][nt] = float4_{0.f, 0.f, 0.f, 0.f};

  // ---- prologue: x-side for t=0
  if (layer == 0) {
    accum_side(acc, xp, wreg[0], nn, quad, wave);
  } else {
    if (tid == 0) {
      poll_ge(go_oth, 1u);                               // h0(0) published
      __builtin_amdgcn_fence(__ATOMIC_ACQUIRE, "agent");
    }
    __syncthreads();
    accum_side(acc, ring_l0 /*slot 0*/, wreg[0], nn, quad, wave);
  }

  #pragma unroll 1
  for (int t = 0; t < T_LEN; ++t) {
    // ---- wait: own-layer h(t-1) ready (+ layer0 ring-reuse gate)
    if (t > 0) {
      if (cb == 0) {
        if (wave == 0)
          leader_wait_publish(slots_own, go_own_w, (unsigned)t, lane);
      } else if (tid == 0) {
        poll_ge(go_own, (unsigned)t);
      }
      if (tid == 0) {
        if (layer == 0 && t >= 8)
          poll_ge(go_oth, (unsigned)(t - 7));
        __builtin_amdgcn_fence(__ATOMIC_ACQUIRE, "agent"); // inv L1/L2
      }
      __syncthreads();
    }

    // ---- recurrent half: h_own(t-1), ring slot (t-1)&7
    accum_side(acc, ring_own + (size_t)((t + 7) & 7) * HB,
               wreg[1], nn, quad, wave);

    // ---- partials -> LDS, gate-permuted col = hcol*4 + gate
    #pragma unroll
    for (int m = 0; m < 4; ++m)
      #pragma unroll
      for (int nt = 0; nt < 2; ++nt)
        #pragma unroll
        for (int r = 0; r < 4; ++r)
          lds[wave][m * 16 + quad * 4 + r]
             [((nn & 7) << 2) + nt * 2 + (nn >> 3)] = acc[m][nt][r];
    __syncthreads();

    // ---- reduce over 8 K-waves + fused elementwise
    float4_ g4 = bias4;
    #pragma unroll
    for (int w = 0; w < 8; ++w)
      g4 += *(const float4_*)&lds[w][rb][rhc << 2];
    const float cprev = (t == 0)
        ? c0_in[(size_t)layer * HB + (size_t)rb * H_SZ + rhcol]
        : creg;
    const float ig = 1.f / (1.f + __expf(-g4[0]));
    const float fg = 1.f / (1.f + __expf(-g4[1]));
    const float gg = tanhf(g4[2]);
    const float og = 1.f / (1.f + __expf(-g4[3]));
    const float cn = fg * cprev + ig * gg;
    const float hn = og * tanhf(cn);
    creg = cn;
    const size_t ridx = (size_t)(layer * 8 + (t & 7)) * HB +
                        (size_t)rb * H_SZ + rhcol;
    const unsigned hh = bf16_rne(hn);
    const unsigned ll = bf16_rne(hn - bf16_to_f32((unsigned short)hh));
    __hip_atomic_store(&ringp[ridx], hh | (ll << 16),
                       __ATOMIC_RELAXED, __HIP_MEMORY_SCOPE_AGENT);
    if (layer == 1 && t == T_LEN - 1)
      out[(size_t)rb * H_SZ + rhcol] = hn;

    // ---- arrive: syncthreads drains all waves' ring stores first
    __syncthreads();
    if (tid == 0) {
      __builtin_amdgcn_s_waitcnt(0);
      __hip_atomic_store(slotp, (unsigned)(t + 1),
                         __ATOMIC_RELAXED, __HIP_MEMORY_SCOPE_AGENT);
    }

    // ---- shadow: x-side for t+1 (overlaps own-barrier propagation)
    if (t < T_LEN - 1) {
      if (layer == 1) {
        if (tid == 0) {
          poll_ge(go_oth, (unsigned)(t + 2));            // h0(t+1) published
          __builtin_amdgcn_fence(__ATOMIC_ACQUIRE, "agent");
        }
        __syncthreads();
      }
      #pragma unroll
      for (int m = 0; m < 4; ++m)
        #pragma unroll
        for (int nt = 0; nt < 2; ++nt)
          acc[m][nt] = float4_{0.f, 0.f, 0.f, 0.f};
      const unsigned* xq = (layer == 0)
          ? (xp + (size_t)(t + 1) * HB)
          : (ring_l0 + (size_t)((t + 1) & 7) * HB);
      accum_side(acc, xq, wreg[0], nn, quad, wave);
    }
  }

  // ---- epilogue: layer-0 leader publishes go0=256 (layer1's last shadow gate)
  if (layer == 0 && cb == 0 && wave == 0)
    leader_wait_publish(slots_own, go_own_w, (unsigned)T_LEN, lane);
}

extern "C" void kernel_launch(void* const* d_in, const int* in_sizes, int n_in,
                              void* d_out, int out_size, void* d_ws, size_t ws_size,
                              hipStream_t stream) {
  (void)in_sizes; (void)n_in; (void)out_size; (void)ws_size;
  const float* x   = (const float*)d_in[0];
  const float* h0  = (const float*)d_in[1];
  const float* c0  = (const float*)d_in[2];
  const float* Wih = (const float*)d_in[3];
  const float* Whh = (const float*)d_in[4];
  const float* bih = (const float*)d_in[5];
  const float* bhh = (const float*)d_in[6];
  float* out = (float*)d_out;

  // workspace (~68.3 MB): xpack 64 MB | ring 4 MB | bar 4 KB
  char* w = (char*)d_ws;
  unsigned* xpack = (unsigned*)w;                                   // T*HB uints
  unsigned* ringp = (unsigned*)(w + (size_t)T_LEN * HB * 4);        // 2L*8slots*HB
  unsigned* bar   = (unsigned*)(w + (size_t)T_LEN * HB * 4
                                  + (size_t)16 * HB * 4);           // 4 KB

  pack_x<<<(T_LEN * HB) / 4 / 256, 256, 0, stream>>>(x, xpack);
  init_h<<<2 * HB / 4 / 256, 256, 0, stream>>>(h0, ringp, bar);
  lstm_persist<<<NBLK, 512, 0, stream>>>(xpack, c0, Wih, Whh, bih, bhh,
                                         ringp, out, bar);
}